// Round 10
// baseline (2404.357 us; speedup 1.0000x reference)
//
#include <hip/hip_runtime.h>
#include <hip/hip_bf16.h>

// MnistModelDP: 2-layer LSTM (H=512) over T=64 frames of 128, B=2048, then proj to 10.
// v9: persistent kernel (v8 structure) with a MEMORY-SAFE coherence scheme:
//  - c state in registers (never touches memory after init)
//  - h in depth-2 rings (8 MB total; v8's 256MB versioned slots overflowed the 256MiB ws
//    -> core dump). Producers store h with agent-scope (sc1) -> at L3 after vmcnt drain.
//  - per-round barrier ends with __builtin_amdgcn_fence(ACQUIRE, "agent") by ALL threads:
//    emits buffer_inv (L1+L2-clean invalidate) per the gfx94x/gfx950 memory model, so
//    subsequent PLAIN CACHED loads are fresh; L2 still filters 8x colgroup h reuse/round.
//  - slab decode: slab=bid&7 owns 256 batch rows of both layers; per-slab barriers (32).
// Tile BM=128 x BN=256, 8 waves, BK=64 dbuf staging via global_load_lds w=16 +
// granule-XOR swizzle (proven v4-v7). fp16 MFMA 16x16x32, fp32 accum.

typedef _Float16 f16x8 __attribute__((ext_vector_type(8)));
typedef float f32x4 __attribute__((ext_vector_type(4)));

#define Bsz 2048
#define Lsz 8192
#define Tsz 64
#define NBLK 256
#define HS ((size_t)Bsz * 512)   // elements per h buffer

__global__ void cvt_f32_f16(const float* __restrict__ src, _Float16* __restrict__ dst, int n4) {
    int stride = gridDim.x * blockDim.x;
    for (int i = blockIdx.x * blockDim.x + threadIdx.x; i < n4; i += stride) {
        float4 v = ((const float4*)src)[i];
        union { _Float16 h[4]; ushort4 u; } o;
        o.h[0] = (_Float16)v.x; o.h[1] = (_Float16)v.y;
        o.h[2] = (_Float16)v.z; o.h[3] = (_Float16)v.w;
        ((ushort4*)dst)[i] = o.u;
    }
}

// pack [2048, K1] W_ih (f32) and [2048, 512] W_hh (f32) -> [2048, K1+512] f16
__global__ void pack_w(const float* __restrict__ Wih, const float* __restrict__ Whh,
                       _Float16* __restrict__ dst, int K1) {
    int KT = K1 + 512;
    int n4 = 2048 * KT / 4;
    int stride = gridDim.x * blockDim.x;
    for (int i = blockIdx.x * blockDim.x + threadIdx.x; i < n4; i += stride) {
        int row = i / (KT / 4);
        int col = (i % (KT / 4)) * 4;
        const float* s = (col < K1) ? (Wih + (size_t)row * K1 + col)
                                    : (Whh + (size_t)row * 512 + (col - K1));
        float4 v = *(const float4*)s;
        union { _Float16 h[4]; ushort4 u; } o;
        o.h[0] = (_Float16)v.x; o.h[1] = (_Float16)v.y;
        o.h[2] = (_Float16)v.z; o.h[3] = (_Float16)v.w;
        ((ushort4*)dst)[i] = o.u;
    }
}

__device__ __forceinline__ float fsig(float x)  { return 1.0f / (1.0f + __expf(-x)); }
__device__ __forceinline__ float ftanh(float x) { return 1.0f - 2.0f / (__expf(2.0f * x) + 1.0f); }

__device__ __forceinline__ void gll16(const _Float16* src, char* dst) {
    __builtin_amdgcn_global_load_lds(
        (const __attribute__((address_space(1))) void*)src,
        (__attribute__((address_space(3))) void*)dst, 16, 0, 0);
}

// Stage one BK=64 K-slice: B (256 gate-cols x 64) at buf+0 (32KB), A (128 rows x 64) at
// buf+32768 (16KB). LDS rows 128 B; slot s of row r holds source granule (s ^ (r&7)) via
// pre-swizzled SOURCE + linear global_load_lds dest (both-sides rule, proven v4-v7).
// Plain cached loads: freshness guaranteed by the round-barrier acquire fence.
template<int K1>
__device__ __forceinline__ void stage_v9(
    const _Float16* __restrict__ A1, int lda1,   // k < K1  (x for layer0, h0 cur for layer1)
    const _Float16* __restrict__ A2,              // k >= K1 (h_prev ring slot or zeros)
    const _Float16* __restrict__ Wcat,            // weights (immutable)
    int hcb, int rowtile, int k0, char* buf, int tid)
{
    constexpr int KT = K1 + 512;
    const int wv = tid >> 6;
    // B tile: rows j = gate*64 + lc -> W row gate*512 + hcb*64 + lc
#pragma unroll
    for (int qq = 0; qq < 4; ++qq) {
        const int j  = qq * 64 + (tid >> 3);
        const int cg = (((tid & 7) ^ (j & 7)) << 3);
        const int wrow = ((j >> 6) << 9) + hcb * 64 + (j & 63);
        gll16(Wcat + (size_t)wrow * KT + k0 + cg, buf + qq * 8192 + wv * 1024);
    }
    // A tile: 128 rows. k0 multiple of 64 and K1 % 64 == 0 -> branch is uniform.
#pragma unroll
    for (int qq = 0; qq < 2; ++qq) {
        const int row  = qq * 64 + (tid >> 3);
        const int cg   = (((tid & 7) ^ (row & 7)) << 3);
        const int brow = rowtile * 128 + row;
        char* d = buf + 32768 + qq * 8192 + wv * 1024;
        if (k0 < K1) gll16(A1 + (size_t)brow * lda1 + k0 + cg, d);
        else         gll16(A2 + (size_t)brow * 512 + (k0 - K1) + cg, d);
    }
}

// One LSTM step tile: 128 batch rows x 256 gate-cols (64 hcols x 4 gates), K = K1+512.
// 8 waves as 2(row) x 4(col) grid of 64x64 wave tiles. BK=64, double-buffered staging.
// c state in registers (creg[8] float2 per thread, fixed cells across all rounds).
// MFMA 16x16x32 f16 layouts (passed v2/v4-v7):
//   A frag: lane l elem j -> A[l&15][(l>>4)*8+j]; B frag: lane l -> W[col l&15][(l>>4)*8+j]
//   C/D: lane l reg r -> C[(l>>4)*4+r][l&15]
template<int K1>
__device__ __forceinline__ void step_v9(
    const _Float16* __restrict__ A1, int lda1,
    const _Float16* __restrict__ A2,
    const _Float16* __restrict__ Wcat,
    const float* __restrict__ bias,
    float2* creg,                         // [8] in registers
    _Float16* __restrict__ h_out,         // ring slot; sc1 stores (visible at L3)
    int rowtile, int hcb, char* lds)
{
    constexpr int KT  = K1 + 512;
    constexpr int NIT = KT / 64;
    const int tid = threadIdx.x;
    const int ln  = tid & 63;
    const int wv  = tid >> 6;
    const int llo = ln & 15, lhi = ln >> 4;
    const int wr  = wv >> 2, wc = wv & 3;   // wave row tile (x64), wave col tile (x64)

    f32x4 acc[4][4] = {};                   // [row-frag mi][col-frag cf]

    stage_v9<K1>(A1, lda1, A2, Wcat, hcb, rowtile, 0, lds, tid);
    __syncthreads();

#pragma unroll 2
    for (int it = 0; it < NIT; ++it) {
        char* cur = lds + (it & 1) * 49152;
        if (it + 1 < NIT)   // prefetch next K-slice into other buffer
            stage_v9<K1>(A1, lda1, A2, Wcat, hcb, rowtile, (it + 1) * 64,
                         lds + ((it + 1) & 1) * 49152, tid);
#pragma unroll
        for (int ks = 0; ks < 2; ++ks) {
            const int gsw = (((ks * 4 + lhi) ^ (llo & 7)) << 4);   // swizzled granule byte
            f16x8 a[4], b[4];
#pragma unroll
            for (int mi = 0; mi < 4; ++mi)
                a[mi] = *(const f16x8*)(cur + 32768 + (wr * 64 + mi * 16 + llo) * 128 + gsw);
#pragma unroll
            for (int cf = 0; cf < 4; ++cf)
                b[cf] = *(const f16x8*)(cur + (wc * 64 + cf * 16 + llo) * 128 + gsw);
#pragma unroll
            for (int mi = 0; mi < 4; ++mi)
#pragma unroll
                for (int cf = 0; cf < 4; ++cf)
                    acc[mi][cf] = __builtin_amdgcn_mfma_f32_16x16x32_f16(
                        a[mi], b[cf], acc[mi][cf], 0, 0, 0);
        }
        __syncthreads();
    }

    // gates exchange: acc -> LDS f32 [128 rows][256 cols] (128 KB overlay, after barrier)
    float* gl = (float*)lds;
#pragma unroll
    for (int mi = 0; mi < 4; ++mi)
#pragma unroll
        for (int cf = 0; cf < 4; ++cf) {
            const int col = wc * 64 + cf * 16 + llo;
#pragma unroll
            for (int rr = 0; rr < 4; ++rr) {
                const int row = wr * 64 + mi * 16 + lhi * 4 + rr;
                gl[row * 256 + col] = acc[mi][cf][rr];
            }
        }
    __syncthreads();

    // fused cell update: 2 adjacent hcols x 8 rows per thread; c from/to registers.
    const int lc2  = (tid & 31) << 1;
    const int ro   = tid >> 5;              // 0..15
    const int hcol = hcb * 64 + lc2;
    const float bi0 = bias[hcol],        bi1 = bias[hcol + 1];
    const float bf0 = bias[512 + hcol],  bf1 = bias[512 + hcol + 1];
    const float bg0 = bias[1024 + hcol], bg1 = bias[1024 + hcol + 1];
    const float bo0 = bias[1536 + hcol], bo1 = bias[1536 + hcol + 1];
#pragma unroll
    for (int i = 0; i < 8; ++i) {
        const int row = i * 16 + ro;
        const float* g0 = gl + row * 256 + lc2;
        float iv0 = g0[0]   + bi0, iv1 = g0[1]   + bi1;
        float fv0 = g0[64]  + bf0, fv1 = g0[65]  + bf1;
        float gv0 = g0[128] + bg0, gv1 = g0[129] + bg1;
        float ov0 = g0[192] + bo0, ov1 = g0[193] + bo1;
        float cn0 = fsig(fv0) * creg[i].x + fsig(iv0) * ftanh(gv0);
        float cn1 = fsig(fv1) * creg[i].y + fsig(iv1) * ftanh(gv1);
        creg[i].x = cn0; creg[i].y = cn1;
        float hn0 = fsig(ov0) * ftanh(cn0);
        float hn1 = fsig(ov1) * ftanh(cn1);
        union { _Float16 h2[2]; unsigned u; } hp;
        hp.h2[0] = (_Float16)hn0; hp.h2[1] = (_Float16)hn1;
        const size_t base = (size_t)(rowtile * 128 + row) * 512 + hcol;
        // agent-scope store -> L3 coherence point (consumers invalidate L2 at the barrier)
        __hip_atomic_store((unsigned*)(h_out + base), hp.u,
                           __ATOMIC_RELAXED, __HIP_MEMORY_SCOPE_AGENT);
    }
}

// Persistent: 256 blocks (1/CU via 128KB LDS). Decode: slab=bid&7 owns batch rows
// [slab*256,+256) for BOTH layers; q=bid>>3: layer=q&1, rt2=(q>>1)&1, hcb=q>>2.
// All h deps slab-local -> per-slab barriers (32 blocks), mapping-agnostic correctness.
__global__ __launch_bounds__(512, 1) void lstm_persist(
    const _Float16* __restrict__ xb16,
    const _Float16* __restrict__ Wc0, const float* __restrict__ b0,
    const _Float16* __restrict__ Wc1, const float* __restrict__ b1,
    _Float16* __restrict__ h0a, _Float16* __restrict__ h0b,   // h0 ring
    _Float16* __restrict__ h1a, _Float16* __restrict__ h1b,   // h1 ring
    const _Float16* __restrict__ hz,                          // zeros
    unsigned* __restrict__ cnt)                               // 8 slab counters, 256B apart
{
    __shared__ __align__(16) char lds[131072];
    const int bid     = blockIdx.x;
    const int slab    = bid & 7;
    const int q       = bid >> 3;
    const int layer   = q & 1;
    const int rowtile = slab * 2 + ((q >> 1) & 1);  // 0..15
    const int hcb     = q >> 2;                     // 0..7

    _Float16* h0r[2] = {h0a, h0b};
    _Float16* h1r[2] = {h1a, h1b};

    float2 creg[8];
#pragma unroll
    for (int i = 0; i < 8; ++i) { creg[i].x = 0.0f; creg[i].y = 0.0f; }

    for (int r = 0; r <= Tsz; ++r) {
        if (layer == 0) {
            if (r < Tsz) {
                const int t = r;
                const _Float16* hp = t ? h0r[(t - 1) & 1] : hz;
                step_v9<128>(xb16 + (size_t)t * 128, Lsz, hp, Wc0, b0, creg,
                             h0r[t & 1], rowtile, hcb, lds);
            }
        } else {
            if (r >= 1) {
                const int t = r - 1;
                const _Float16* h0in = h0r[t & 1];          // h0 output of step t
                const _Float16* hp   = t ? h1r[(t - 1) & 1] : hz;
                step_v9<512>(h0in, 512, hp, Wc1, b1, creg,
                             h1r[t & 1], rowtile, hcb, lds);
            }
        }
        if (r < Tsz) {
            // per-slab barrier. __syncthreads drains vmcnt (sc1 h stores at L3);
            // monotonic counter arrive/spin; acquire-agent fence by ALL threads emits
            // buffer_inv (L1+L2-clean invalidate) -> plain cached loads below are fresh.
            __syncthreads();
            if (threadIdx.x == 0) {
                unsigned* cp = cnt + slab * 64;
                __hip_atomic_fetch_add(cp, 1u, __ATOMIC_RELAXED, __HIP_MEMORY_SCOPE_AGENT);
                const unsigned target = 32u * (r + 1);
                while (__hip_atomic_load(cp, __ATOMIC_RELAXED, __HIP_MEMORY_SCOPE_AGENT) < target)
                    __builtin_amdgcn_s_sleep(1);
            }
            __syncthreads();
            __builtin_amdgcn_fence(__ATOMIC_ACQUIRE, "agent");
            __builtin_amdgcn_sched_barrier(0);
        }
    }
}

__global__ void proj_kernel(const _Float16* __restrict__ h1,
                            const float* __restrict__ Wout,  // [10, 512]
                            const float* __restrict__ bout,  // [10]
                            float* __restrict__ out)         // [2048, 10]
{
    int tid = blockIdx.x * blockDim.x + threadIdx.x;
    if (tid >= Bsz * 10) return;
    int b = tid / 10, o = tid % 10;
    float s = bout[o];
    const _Float16* hrow = h1 + (size_t)b * 512;
    const float* wrow = Wout + (size_t)o * 512;
    for (int k = 0; k < 512; ++k) s += (float)hrow[k] * wrow[k];
    out[tid] = s;
}

extern "C" void kernel_launch(void* const* d_in, const int* in_sizes, int n_in,
                              void* d_out, int out_size, void* d_ws, size_t ws_size,
                              hipStream_t stream) {
    const float* xb    = (const float*)d_in[0];
    const float* W_ih0 = (const float*)d_in[1];
    const float* W_hh0 = (const float*)d_in[2];
    const float* b0    = (const float*)d_in[3];
    const float* W_ih1 = (const float*)d_in[4];
    const float* W_hh1 = (const float*)d_in[5];
    const float* b1    = (const float*)d_in[6];
    const float* W_out = (const float*)d_in[7];
    const float* b_out = (const float*)d_in[8];
    float* out = (float*)d_out;

    char* ws = (char*)d_ws;
    size_t off = 0;
    auto alloc = [&](size_t bytes) -> void* {
        void* p = ws + off;
        off += (bytes + 255) & ~(size_t)255;
        return p;
    };
    // total ~47 MB << 256 MiB ws (v8 overflowed with 297 MB -> crash)
    _Float16* xb16 = (_Float16*)alloc((size_t)Bsz * Lsz * 2);      // 32 MB
    _Float16* Wc0  = (_Float16*)alloc((size_t)2048 * 640 * 2);
    _Float16* Wc1  = (_Float16*)alloc((size_t)2048 * 1024 * 2);
    _Float16* h0a  = (_Float16*)alloc(HS * 2);
    _Float16* h0b  = (_Float16*)alloc(HS * 2);
    _Float16* h1a  = (_Float16*)alloc(HS * 2);
    _Float16* h1b  = (_Float16*)alloc(HS * 2);
    _Float16* hz   = (_Float16*)alloc(HS * 2);
    unsigned* cnt  = (unsigned*)alloc(8 * 256);

    cvt_f32_f16<<<2048, 256, 0, stream>>>(xb, xb16, Bsz * Lsz / 4);
    pack_w<<<1280, 256, 0, stream>>>(W_ih0, W_hh0, Wc0, 128);
    pack_w<<<2048, 256, 0, stream>>>(W_ih1, W_hh1, Wc1, 512);

    hipMemsetAsync(hz, 0, HS * 2, stream);
    hipMemsetAsync(cnt, 0, 8 * 256, stream);   // barrier counters: reset every launch

    lstm_persist<<<dim3(NBLK), 512, 0, stream>>>(
        xb16, Wc0, b0, Wc1, b1, h0a, h0b, h1a, h1b, hz, cnt);

    // final h1 = step t=63 -> h1r[63&1] = h1b
    proj_kernel<<<(Bsz * 10 + 255) / 256, 256, 0, stream>>>(h1b, W_out, b_out, out);
}

// Round 11
// 1852.034 us; speedup vs baseline: 1.2982x; 1.2982x over previous
//
#include <hip/hip_runtime.h>
#include <hip/hip_bf16.h>

// MnistModelDP: 2-layer LSTM (H=512) over T=64 frames of 128, B=2048, then proj to 10.
// v10: persistent kernel, composition of verified pieces:
//  - c state in registers (v9; WRITE_SIZE confirmed)
//  - h coherence via sc1 (device-scope) on BOTH sides (v7 scheme, HW-validated): producer
//    sc1 stores to IF coherence point, consumer sc1 global_load_lds. NO fence -> weights/x
//    stay L2-resident forever (v9's per-round buffer_inv was the 29MB/round refetch).
//  - counted-vmcnt K-loop (T3/T4): raw s_barrier + s_waitcnt vmcnt(8/6/0), never drain
//    mid-loop; A triple-buffered (2-deep prefetch covers ~900cy IF latency of sc1 h loads),
//    B double-buffered. LDS 112KB staging + stride-258 padded f32 exchange overlay.
// Tile BM=128 x BN=256 per block, 8 waves (2x4 of 64x64), BK=64, granule-XOR swizzle
// via pre-swizzled source + linear global_load_lds dest (proven v4-v9). fp16 MFMA.

typedef _Float16 f16x8 __attribute__((ext_vector_type(8)));
typedef float f32x4 __attribute__((ext_vector_type(4)));

#define Bsz 2048
#define Lsz 8192
#define Tsz 64
#define NBLK 256
#define HS ((size_t)Bsz * 512)
#define XSTR 258   // exchange row stride (f32): 258%32=2 -> bank-conflict-free write/read

__global__ void cvt_f32_f16(const float* __restrict__ src, _Float16* __restrict__ dst, int n4) {
    int stride = gridDim.x * blockDim.x;
    for (int i = blockIdx.x * blockDim.x + threadIdx.x; i < n4; i += stride) {
        float4 v = ((const float4*)src)[i];
        union { _Float16 h[4]; ushort4 u; } o;
        o.h[0] = (_Float16)v.x; o.h[1] = (_Float16)v.y;
        o.h[2] = (_Float16)v.z; o.h[3] = (_Float16)v.w;
        ((ushort4*)dst)[i] = o.u;
    }
}

// pack [2048, K1] W_ih (f32) and [2048, 512] W_hh (f32) -> [2048, K1+512] f16
__global__ void pack_w(const float* __restrict__ Wih, const float* __restrict__ Whh,
                       _Float16* __restrict__ dst, int K1) {
    int KT = K1 + 512;
    int n4 = 2048 * KT / 4;
    int stride = gridDim.x * blockDim.x;
    for (int i = blockIdx.x * blockDim.x + threadIdx.x; i < n4; i += stride) {
        int row = i / (KT / 4);
        int col = (i % (KT / 4)) * 4;
        const float* s = (col < K1) ? (Wih + (size_t)row * K1 + col)
                                    : (Whh + (size_t)row * 512 + (col - K1));
        float4 v = *(const float4*)s;
        union { _Float16 h[4]; ushort4 u; } o;
        o.h[0] = (_Float16)v.x; o.h[1] = (_Float16)v.y;
        o.h[2] = (_Float16)v.z; o.h[3] = (_Float16)v.w;
        ((ushort4*)dst)[i] = o.u;
    }
}

__device__ __forceinline__ float fsig(float x)  { return 1.0f / (1.0f + __expf(-x)); }
__device__ __forceinline__ float ftanh(float x) { return 1.0f - 2.0f / (__expf(2.0f * x) + 1.0f); }

// AUX=0: plain cached (weights/x). AUX=16 (SC1): device scope -> L2 bypass, IF coherent (h).
template<int AUX>
__device__ __forceinline__ void gll16(const _Float16* src, char* dst) {
    __builtin_amdgcn_global_load_lds(
        (const __attribute__((address_space(1))) void*)src,
        (__attribute__((address_space(3))) void*)dst, 16, 0, AUX);
}

// B tile (256 gate-cols x 64, 32KB): 4 gll/thread. Granule-XOR swizzle via source addr.
template<int K1>
__device__ __forceinline__ void stageB(
    const _Float16* __restrict__ Wcat, int hcb, int k0, char* buf, int tid)
{
    constexpr int KT = K1 + 512;
    const int wv = tid >> 6;
#pragma unroll
    for (int qq = 0; qq < 4; ++qq) {
        const int j  = qq * 64 + (tid >> 3);
        const int cg = (((tid & 7) ^ (j & 7)) << 3);
        const int wrow = ((j >> 6) << 9) + hcb * 64 + (j & 63);
        gll16<0>(Wcat + (size_t)wrow * KT + k0 + cg, buf + qq * 8192 + wv * 1024);
    }
}

// A tile (128 rows x 64, 16KB): 2 gll/thread. k0 multiple of 64, K1%64==0 -> uniform branch.
template<int K1, int AUX1>
__device__ __forceinline__ void stageA(
    const _Float16* __restrict__ A1, int lda1,   // x (plain) for layer0; h0 (sc1) for layer1
    const _Float16* __restrict__ A2,              // h_prev (sc1)
    int rowtile, int k0, char* buf, int tid)
{
    const int wv = tid >> 6;
#pragma unroll
    for (int qq = 0; qq < 2; ++qq) {
        const int row  = qq * 64 + (tid >> 3);
        const int cg   = (((tid & 7) ^ (row & 7)) << 3);
        const int brow = rowtile * 128 + row;
        char* d = buf + qq * 8192 + wv * 1024;
        if (k0 < K1) gll16<AUX1>(A1 + (size_t)brow * lda1 + k0 + cg, d);
        else         gll16<16>(A2 + (size_t)brow * 512 + (k0 - K1) + cg, d);
    }
}

// One LSTM step tile: 128 rows x 256 gate-cols (64 hcols x 4 gates), K = K1+512, BK=64.
// Counted-vmcnt pipeline: issue order per it = [B(it+1), A(it+2)]; prologue [A0,B0,A1].
// Wait before compute(it): vmcnt(8) steady / 6 at NIT-2 / 0 at NIT-1 (= loads issued
// after tile it). Raw s_barrier, no mid-loop drain. A ring depth 3, B depth 2.
// MFMA 16x16x32 f16 layouts (passed v2/v4-v9):
//   A frag: lane l elem j -> A[l&15][(l>>4)*8+j]; B frag: lane l -> W[col l&15][(l>>4)*8+j]
//   C/D: lane l reg r -> C[(l>>4)*4+r][l&15]
template<int K1, int AUX1>
__device__ __forceinline__ void step_v10(
    const _Float16* __restrict__ A1, int lda1,
    const _Float16* __restrict__ A2,
    const _Float16* __restrict__ Wcat,
    const float* __restrict__ bias,
    float2* creg,                         // [8] in registers
    _Float16* __restrict__ h_out,         // sc1 stores -> IF
    int rowtile, int hcb, char* lds)
{
    constexpr int KT  = K1 + 512;
    constexpr int NIT = KT / 64;
    const int tid = threadIdx.x;
    const int ln  = tid & 63;
    const int wv  = tid >> 6;
    const int llo = ln & 15, lhi = ln >> 4;
    const int wr  = wv >> 2, wc = wv & 3;

    f32x4 acc[4][4] = {};

    // prologue: A0, B0, A1  (order matters for the vmcnt arithmetic)
    stageA<K1, AUX1>(A1, lda1, A2, rowtile, 0, lds + 65536, tid);
    stageB<K1>(Wcat, hcb, 0, lds, tid);
    if (NIT > 1) stageA<K1, AUX1>(A1, lda1, A2, rowtile, 64, lds + 65536 + 16384, tid);

    for (int it = 0; it < NIT; ++it) {
        // issue next tiles (B first, then A — matches the wait arithmetic)
        if (it + 1 < NIT)
            stageB<K1>(Wcat, hcb, (it + 1) * 64, lds + ((it + 1) & 1) * 32768, tid);
        if (it + 2 < NIT)
            stageA<K1, AUX1>(A1, lda1, A2, rowtile, (it + 2) * 64,
                             lds + 65536 + ((it + 2) % 3) * 16384, tid);
        // counted wait: after-tile-it loads = 8 steady, 6 at NIT-2, 0 at NIT-1
        if (it < NIT - 2)       asm volatile("s_waitcnt vmcnt(8)" ::: "memory");
        else if (it == NIT - 2) asm volatile("s_waitcnt vmcnt(6)" ::: "memory");
        else                    asm volatile("s_waitcnt vmcnt(0)" ::: "memory");
        __builtin_amdgcn_s_barrier();
        __builtin_amdgcn_sched_barrier(0);

        char* bb = lds + (it & 1) * 32768;
        char* ab = lds + 65536 + (it % 3) * 16384;
#pragma unroll
        for (int ks = 0; ks < 2; ++ks) {
            const int gsw = (((ks * 4 + lhi) ^ (llo & 7)) << 4);
            f16x8 a[4], b[4];
#pragma unroll
            for (int mi = 0; mi < 4; ++mi)
                a[mi] = *(const f16x8*)(ab + (wr * 64 + mi * 16 + llo) * 128 + gsw);
#pragma unroll
            for (int cf = 0; cf < 4; ++cf)
                b[cf] = *(const f16x8*)(bb + (wc * 64 + cf * 16 + llo) * 128 + gsw);
#pragma unroll
            for (int mi = 0; mi < 4; ++mi)
#pragma unroll
                for (int cf = 0; cf < 4; ++cf)
                    acc[mi][cf] = __builtin_amdgcn_mfma_f32_16x16x32_f16(
                        a[mi], b[cf], acc[mi][cf], 0, 0, 0);
        }
        __builtin_amdgcn_s_barrier();        // readers done before next it overwrites
        __builtin_amdgcn_sched_barrier(0);
    }

    // gates exchange: acc -> LDS f32 [128][XSTR] overlay (all staging drained: vmcnt(0)
    // at final it + trailing barrier)
    float* gl = (float*)lds;
#pragma unroll
    for (int mi = 0; mi < 4; ++mi)
#pragma unroll
        for (int cf = 0; cf < 4; ++cf) {
            const int col = wc * 64 + cf * 16 + llo;
#pragma unroll
            for (int rr = 0; rr < 4; ++rr) {
                const int row = wr * 64 + mi * 16 + lhi * 4 + rr;
                gl[row * XSTR + col] = acc[mi][cf][rr];
            }
        }
    __syncthreads();

    // fused cell update: 2 adjacent hcols x 8 rows per thread; c in registers.
    const int lc2  = (tid & 31) << 1;
    const int ro   = tid >> 5;
    const int hcol = hcb * 64 + lc2;
    const float bi0 = bias[hcol],        bi1 = bias[hcol + 1];
    const float bf0 = bias[512 + hcol],  bf1 = bias[512 + hcol + 1];
    const float bg0 = bias[1024 + hcol], bg1 = bias[1024 + hcol + 1];
    const float bo0 = bias[1536 + hcol], bo1 = bias[1536 + hcol + 1];
#pragma unroll
    for (int i = 0; i < 8; ++i) {
        const int row = i * 16 + ro;
        const float* g0 = gl + row * XSTR + lc2;
        float iv0 = g0[0]   + bi0, iv1 = g0[1]   + bi1;
        float fv0 = g0[64]  + bf0, fv1 = g0[65]  + bf1;
        float gv0 = g0[128] + bg0, gv1 = g0[129] + bg1;
        float ov0 = g0[192] + bo0, ov1 = g0[193] + bo1;
        float cn0 = fsig(fv0) * creg[i].x + fsig(iv0) * ftanh(gv0);
        float cn1 = fsig(fv1) * creg[i].y + fsig(iv1) * ftanh(gv1);
        creg[i].x = cn0; creg[i].y = cn1;
        float hn0 = fsig(ov0) * ftanh(cn0);
        float hn1 = fsig(ov1) * ftanh(cn1);
        union { _Float16 h2[2]; unsigned u; } hp;
        hp.h2[0] = (_Float16)hn0; hp.h2[1] = (_Float16)hn1;
        const size_t base = (size_t)(rowtile * 128 + row) * 512 + hcol;
        __hip_atomic_store((unsigned*)(h_out + base), hp.u,
                           __ATOMIC_RELAXED, __HIP_MEMORY_SCOPE_AGENT);
    }
}

// Persistent: 256 blocks. slab=bid&7 owns batch rows [slab*256,+256) of both layers;
// q=bid>>3: layer=q&1, rowtile=slab*2+((q>>1)&1), hcb=q>>2. Per-slab barriers (32 blocks).
// Correctness mapping-agnostic: all cross-block h traffic goes through IF (sc1 both sides).
__global__ __launch_bounds__(512, 1) void lstm_persist(
    const _Float16* __restrict__ xb16,
    const _Float16* __restrict__ Wc0, const float* __restrict__ b0,
    const _Float16* __restrict__ Wc1, const float* __restrict__ b1,
    _Float16* __restrict__ h0a, _Float16* __restrict__ h0b,
    _Float16* __restrict__ h1a, _Float16* __restrict__ h1b,
    const _Float16* __restrict__ hz,
    unsigned* __restrict__ cnt)
{
    __shared__ __align__(16) char lds[132096];   // max(112KB staging, 128*258*4 exchange)
    const int bid     = blockIdx.x;
    const int slab    = bid & 7;
    const int q       = bid >> 3;
    const int layer   = q & 1;
    const int rowtile = slab * 2 + ((q >> 1) & 1);
    const int hcb     = q >> 2;

    _Float16* h0r[2] = {h0a, h0b};
    _Float16* h1r[2] = {h1a, h1b};

    float2 creg[8];
#pragma unroll
    for (int i = 0; i < 8; ++i) { creg[i].x = 0.0f; creg[i].y = 0.0f; }

    for (int r = 0; r <= Tsz; ++r) {
        if (layer == 0) {
            if (r < Tsz) {
                const int t = r;
                const _Float16* hp = t ? h0r[(t - 1) & 1] : hz;
                step_v10<128, 0>(xb16 + (size_t)t * 128, Lsz, hp, Wc0, b0, creg,
                                 h0r[t & 1], rowtile, hcb, lds);
            }
        } else {
            if (r >= 1) {
                const int t = r - 1;
                const _Float16* h0in = h0r[t & 1];
                const _Float16* hp   = t ? h1r[(t - 1) & 1] : hz;
                step_v10<512, 16>(h0in, 512, hp, Wc1, b1, creg,
                                  h1r[t & 1], rowtile, hcb, lds);
            }
        }
        if (r < Tsz) {
            // per-slab barrier: __syncthreads drains vmcnt (sc1 h stores at IF), then
            // monotonic counter arrive/spin (relaxed agent atomics). No cache fence.
            __syncthreads();
            if (threadIdx.x == 0) {
                unsigned* cp = cnt + slab * 64;
                __hip_atomic_fetch_add(cp, 1u, __ATOMIC_RELAXED, __HIP_MEMORY_SCOPE_AGENT);
                const unsigned target = 32u * (r + 1);
                while (__hip_atomic_load(cp, __ATOMIC_RELAXED, __HIP_MEMORY_SCOPE_AGENT) < target)
                    __builtin_amdgcn_s_sleep(1);
            }
            __syncthreads();
            __builtin_amdgcn_sched_barrier(0);
        }
    }
}

__global__ void proj_kernel(const _Float16* __restrict__ h1,
                            const float* __restrict__ Wout,  // [10, 512]
                            const float* __restrict__ bout,  // [10]
                            float* __restrict__ out)         // [2048, 10]
{
    int tid = blockIdx.x * blockDim.x + threadIdx.x;
    if (tid >= Bsz * 10) return;
    int b = tid / 10, o = tid % 10;
    float s = bout[o];
    const _Float16* hrow = h1 + (size_t)b * 512;
    const float* wrow = Wout + (size_t)o * 512;
    for (int k = 0; k < 512; ++k) s += (float)hrow[k] * wrow[k];
    out[tid] = s;
}

extern "C" void kernel_launch(void* const* d_in, const int* in_sizes, int n_in,
                              void* d_out, int out_size, void* d_ws, size_t ws_size,
                              hipStream_t stream) {
    const float* xb    = (const float*)d_in[0];
    const float* W_ih0 = (const float*)d_in[1];
    const float* W_hh0 = (const float*)d_in[2];
    const float* b0    = (const float*)d_in[3];
    const float* W_ih1 = (const float*)d_in[4];
    const float* W_hh1 = (const float*)d_in[5];
    const float* b1    = (const float*)d_in[6];
    const float* W_out = (const float*)d_in[7];
    const float* b_out = (const float*)d_in[8];
    float* out = (float*)d_out;

    char* ws = (char*)d_ws;
    size_t off = 0;
    auto alloc = [&](size_t bytes) -> void* {
        void* p = ws + off;
        off += (bytes + 255) & ~(size_t)255;
        return p;
    };
    // total ~47 MB << 256 MiB ws
    _Float16* xb16 = (_Float16*)alloc((size_t)Bsz * Lsz * 2);
    _Float16* Wc0  = (_Float16*)alloc((size_t)2048 * 640 * 2);
    _Float16* Wc1  = (_Float16*)alloc((size_t)2048 * 1024 * 2);
    _Float16* h0a  = (_Float16*)alloc(HS * 2);
    _Float16* h0b  = (_Float16*)alloc(HS * 2);
    _Float16* h1a  = (_Float16*)alloc(HS * 2);
    _Float16* h1b  = (_Float16*)alloc(HS * 2);
    _Float16* hz   = (_Float16*)alloc(HS * 2);
    unsigned* cnt  = (unsigned*)alloc(8 * 256);

    cvt_f32_f16<<<2048, 256, 0, stream>>>(xb, xb16, Bsz * Lsz / 4);
    pack_w<<<1280, 256, 0, stream>>>(W_ih0, W_hh0, Wc0, 128);
    pack_w<<<2048, 256, 0, stream>>>(W_ih1, W_hh1, Wc1, 512);

    hipMemsetAsync(hz, 0, HS * 2, stream);
    hipMemsetAsync(cnt, 0, 8 * 256, stream);   // barrier counters reset every launch

    lstm_persist<<<dim3(NBLK), 512, 0, stream>>>(
        xb16, Wc0, b0, Wc1, b1, h0a, h0b, h1a, h1b, hz, cnt);

    // final h1 = step t=63 -> h1r[63&1] = h1b
    proj_kernel<<<(Bsz * 10 + 255) / 256, 256, 0, stream>>>(h1b, W_out, b_out, out);
}

// Round 12
// 1644.960 us; speedup vs baseline: 1.4617x; 1.1259x over previous
//
#include <hip/hip_runtime.h>
#include <hip/hip_bf16.h>

// MnistModelDP: 2-layer LSTM (H=512) over T=64 frames of 128, B=2048, then proj to 10.
// v11: launch-per-round (kernel-boundary coherence: plain cached loads/stores everywhere,
// no sc1, no fences — v6's scheme, best so far) + counted-vmcnt K-loop (v10's verified
// pipeline: B double-buffered, A triple-buffered, s_waitcnt vmcnt(8/6/0), raw s_barrier,
// loads stay in flight across iters — removes the per-iter vmcnt(0) barrier drain that
// capped v4-v6 at ~24us/round). Tile BM=128 x BN=256 (64 hcols x 4 gates), 8 waves,
// BK=64, granule-XOR swizzle via pre-swizzled source + linear global_load_lds dest.
// hcb=bid&7 decode pins one 832KB weight strip pair per XCD. fp16 MFMA, fp32 accum,
// c fp32 in global (round-trips via L2/IF), h f16 double-buffered rings.

typedef _Float16 f16x8 __attribute__((ext_vector_type(8)));
typedef float f32x4 __attribute__((ext_vector_type(4)));

#define Bsz 2048
#define Lsz 8192
#define Tsz 64
#define XSTR 258   // exchange row stride (f32), bank-conflict-free

__global__ void cvt_f32_f16(const float* __restrict__ src, _Float16* __restrict__ dst, int n4) {
    int stride = gridDim.x * blockDim.x;
    for (int i = blockIdx.x * blockDim.x + threadIdx.x; i < n4; i += stride) {
        float4 v = ((const float4*)src)[i];
        union { _Float16 h[4]; ushort4 u; } o;
        o.h[0] = (_Float16)v.x; o.h[1] = (_Float16)v.y;
        o.h[2] = (_Float16)v.z; o.h[3] = (_Float16)v.w;
        ((ushort4*)dst)[i] = o.u;
    }
}

// pack [2048, K1] W_ih (f32) and [2048, 512] W_hh (f32) -> [2048, K1+512] f16
__global__ void pack_w(const float* __restrict__ Wih, const float* __restrict__ Whh,
                       _Float16* __restrict__ dst, int K1) {
    int KT = K1 + 512;
    int n4 = 2048 * KT / 4;
    int stride = gridDim.x * blockDim.x;
    for (int i = blockIdx.x * blockDim.x + threadIdx.x; i < n4; i += stride) {
        int row = i / (KT / 4);
        int col = (i % (KT / 4)) * 4;
        const float* s = (col < K1) ? (Wih + (size_t)row * K1 + col)
                                    : (Whh + (size_t)row * 512 + (col - K1));
        float4 v = *(const float4*)s;
        union { _Float16 h[4]; ushort4 u; } o;
        o.h[0] = (_Float16)v.x; o.h[1] = (_Float16)v.y;
        o.h[2] = (_Float16)v.z; o.h[3] = (_Float16)v.w;
        ((ushort4*)dst)[i] = o.u;
    }
}

__device__ __forceinline__ float fsig(float x)  { return 1.0f / (1.0f + __expf(-x)); }
__device__ __forceinline__ float ftanh(float x) { return 1.0f - 2.0f / (__expf(2.0f * x) + 1.0f); }

__device__ __forceinline__ void gll16(const _Float16* src, char* dst) {
    __builtin_amdgcn_global_load_lds(
        (const __attribute__((address_space(1))) void*)src,
        (__attribute__((address_space(3))) void*)dst, 16, 0, 0);
}

// B tile (256 gate-cols x 64, 32KB): 4 gll/thread. Granule-XOR swizzle via source addr.
template<int K1>
__device__ __forceinline__ void stageB(
    const _Float16* __restrict__ Wcat, int hcb, int k0, char* buf, int tid)
{
    constexpr int KT = K1 + 512;
    const int wv = tid >> 6;
#pragma unroll
    for (int qq = 0; qq < 4; ++qq) {
        const int j  = qq * 64 + (tid >> 3);
        const int cg = (((tid & 7) ^ (j & 7)) << 3);
        const int wrow = ((j >> 6) << 9) + hcb * 64 + (j & 63);
        gll16(Wcat + (size_t)wrow * KT + k0 + cg, buf + qq * 8192 + wv * 1024);
    }
}

// A tile (128 rows x 64, 16KB): 2 gll/thread. k0 mult of 64, K1%64==0 -> uniform branch.
template<int K1>
__device__ __forceinline__ void stageA(
    const _Float16* __restrict__ A1, int lda1,
    const _Float16* __restrict__ A2,
    int rowtile, int k0, char* buf, int tid)
{
    const int wv = tid >> 6;
#pragma unroll
    for (int qq = 0; qq < 2; ++qq) {
        const int row  = qq * 64 + (tid >> 3);
        const int cg   = (((tid & 7) ^ (row & 7)) << 3);
        const int brow = rowtile * 128 + row;
        char* d = buf + qq * 8192 + wv * 1024;
        if (k0 < K1) gll16(A1 + (size_t)brow * lda1 + k0 + cg, d);
        else         gll16(A2 + (size_t)brow * 512 + (k0 - K1) + cg, d);
    }
}

// One LSTM step tile: 128 rows x 256 gate-cols (64 hcols x 4 gates), K = K1+512, BK=64.
// Counted-vmcnt pipeline (verified v10): prologue [A0,B0,A1]; per it issue [B(it+1),
// A(it+2)]; wait vmcnt(8) steady / 6 at NIT-2 / 0 at NIT-1; raw s_barrier; no mid-loop
// drain. A ring depth 3 (@65536), B depth 2 (@0).
// MFMA 16x16x32 f16 layouts (passed v2/v4-v10):
//   A frag: lane l elem j -> A[l&15][(l>>4)*8+j]; B frag: lane l -> W[col l&15][(l>>4)*8+j]
//   C/D: lane l reg r -> C[(l>>4)*4+r][l&15]
template<int K1>
__device__ __forceinline__ void step_v11(
    const _Float16* __restrict__ A1, int lda1,
    const _Float16* __restrict__ A2,
    const _Float16* __restrict__ Wcat,
    const float* __restrict__ bias,
    float* __restrict__ c,                // [2048][512] fp32 in/out (global)
    _Float16* __restrict__ h_out,         // plain stores (kernel-boundary coherence)
    int rowtile, int hcb, char* lds)
{
    constexpr int KT  = K1 + 512;
    constexpr int NIT = KT / 64;
    const int tid = threadIdx.x;
    const int ln  = tid & 63;
    const int wv  = tid >> 6;
    const int llo = ln & 15, lhi = ln >> 4;
    const int wr  = wv >> 2, wc = wv & 3;

    f32x4 acc[4][4] = {};

    // prologue: A0, B0, A1 (order matters for vmcnt arithmetic)
    stageA<K1>(A1, lda1, A2, rowtile, 0, lds + 65536, tid);
    stageB<K1>(Wcat, hcb, 0, lds, tid);
    stageA<K1>(A1, lda1, A2, rowtile, 64, lds + 65536 + 16384, tid);

    for (int it = 0; it < NIT; ++it) {
        if (it + 1 < NIT)
            stageB<K1>(Wcat, hcb, (it + 1) * 64, lds + ((it + 1) & 1) * 32768, tid);
        if (it + 2 < NIT)
            stageA<K1>(A1, lda1, A2, rowtile, (it + 2) * 64,
                       lds + 65536 + ((it + 2) % 3) * 16384, tid);
        // after-tile-it outstanding loads: 8 steady (A+1,B+1,A+2), 6 at NIT-2, 0 at NIT-1
        if (it < NIT - 2)       asm volatile("s_waitcnt vmcnt(8)" ::: "memory");
        else if (it == NIT - 2) asm volatile("s_waitcnt vmcnt(6)" ::: "memory");
        else                    asm volatile("s_waitcnt vmcnt(0)" ::: "memory");
        __builtin_amdgcn_s_barrier();
        __builtin_amdgcn_sched_barrier(0);

        char* bb = lds + (it & 1) * 32768;
        char* ab = lds + 65536 + (it % 3) * 16384;
#pragma unroll
        for (int ks = 0; ks < 2; ++ks) {
            const int gsw = (((ks * 4 + lhi) ^ (llo & 7)) << 4);
            f16x8 a[4], b[4];
#pragma unroll
            for (int mi = 0; mi < 4; ++mi)
                a[mi] = *(const f16x8*)(ab + (wr * 64 + mi * 16 + llo) * 128 + gsw);
#pragma unroll
            for (int cf = 0; cf < 4; ++cf)
                b[cf] = *(const f16x8*)(bb + (wc * 64 + cf * 16 + llo) * 128 + gsw);
#pragma unroll
            for (int mi = 0; mi < 4; ++mi)
#pragma unroll
                for (int cf = 0; cf < 4; ++cf)
                    acc[mi][cf] = __builtin_amdgcn_mfma_f32_16x16x32_f16(
                        a[mi], b[cf], acc[mi][cf], 0, 0, 0);
        }
        __builtin_amdgcn_s_barrier();        // readers done before next overwrite
        __builtin_amdgcn_sched_barrier(0);
    }

    // gates exchange: acc -> LDS f32 [128][XSTR] overlay (staging fully drained above)
    float* gl = (float*)lds;
#pragma unroll
    for (int mi = 0; mi < 4; ++mi)
#pragma unroll
        for (int cf = 0; cf < 4; ++cf) {
            const int col = wc * 64 + cf * 16 + llo;
#pragma unroll
            for (int rr = 0; rr < 4; ++rr) {
                const int row = wr * 64 + mi * 16 + lhi * 4 + rr;
                gl[row * XSTR + col] = acc[mi][cf][rr];
            }
        }
    __syncthreads();

    // fused cell update: 2 adjacent hcols x 8 rows per thread; c via global f32.
    const int lc2  = (tid & 31) << 1;
    const int ro   = tid >> 5;
    const int hcol = hcb * 64 + lc2;
    const float bi0 = bias[hcol],        bi1 = bias[hcol + 1];
    const float bf0 = bias[512 + hcol],  bf1 = bias[512 + hcol + 1];
    const float bg0 = bias[1024 + hcol], bg1 = bias[1024 + hcol + 1];
    const float bo0 = bias[1536 + hcol], bo1 = bias[1536 + hcol + 1];
#pragma unroll
    for (int i = 0; i < 8; ++i) {
        const int row = i * 16 + ro;
        const float* g0 = gl + row * XSTR + lc2;
        float iv0 = g0[0]   + bi0, iv1 = g0[1]   + bi1;
        float fv0 = g0[64]  + bf0, fv1 = g0[65]  + bf1;
        float gv0 = g0[128] + bg0, gv1 = g0[129] + bg1;
        float ov0 = g0[192] + bo0, ov1 = g0[193] + bo1;
        const size_t base = (size_t)(rowtile * 128 + row) * 512 + hcol;
        float2 cc = *(const float2*)&c[base];
        float cn0 = fsig(fv0) * cc.x + fsig(iv0) * ftanh(gv0);
        float cn1 = fsig(fv1) * cc.y + fsig(iv1) * ftanh(gv1);
        float2 cw; cw.x = cn0; cw.y = cn1;
        *(float2*)&c[base] = cw;
        float hn0 = fsig(ov0) * ftanh(cn0);
        float hn1 = fsig(ov1) * ftanh(cn1);
        union { _Float16 h2[2]; unsigned u; } hp;
        hp.h2[0] = (_Float16)hn0; hp.h2[1] = (_Float16)hn1;
        *(unsigned*)(h_out + base) = hp.u;
    }
}

// Paired round: 256 blocks. hcb = bid&7 (one weight strip pair per XCD under default
// round-robin; correctness mapping-independent). q = bid>>3: layer = q&1, rowtile = q>>1.
__global__ __launch_bounds__(512, 1) void lstm_round(
    int t0, int t1,
    const _Float16* __restrict__ xb16,
    const _Float16* __restrict__ Wc0, const float* __restrict__ b0, float* __restrict__ c0,
    _Float16* __restrict__ h00, _Float16* __restrict__ h01,
    const _Float16* __restrict__ Wc1, const float* __restrict__ b1, float* __restrict__ c1,
    _Float16* __restrict__ h10, _Float16* __restrict__ h11)
{
    __shared__ __align__(16) char lds[132096];   // 112KB staging / 129KB exchange overlay
    const int bid     = blockIdx.x;
    const int hcb     = bid & 7;
    const int q       = bid >> 3;
    const int layer   = q & 1;
    const int rowtile = q >> 1;   // 0..15

    if (layer == 0) {
        if (t0 < 0) return;
        const _Float16* hr = (t0 & 1) ? h01 : h00;
        _Float16*       hw = (t0 & 1) ? h00 : h01;
        step_v11<128>(xb16 + (size_t)t0 * 128, Lsz, hr, Wc0, b0, c0, hw, rowtile, hcb, lds);
    } else {
        if (t1 < 0) return;
        const _Float16* h0in = ((t1 + 1) & 1) ? h01 : h00;  // h0 output of step t1
        const _Float16* hr   = (t1 & 1) ? h11 : h10;
        _Float16*       hw   = (t1 & 1) ? h10 : h11;
        step_v11<512>(h0in, 512, hr, Wc1, b1, c1, hw, rowtile, hcb, lds);
    }
}

__global__ void proj_kernel(const _Float16* __restrict__ h1,
                            const float* __restrict__ Wout,  // [10, 512]
                            const float* __restrict__ bout,  // [10]
                            float* __restrict__ out)         // [2048, 10]
{
    int tid = blockIdx.x * blockDim.x + threadIdx.x;
    if (tid >= Bsz * 10) return;
    int b = tid / 10, o = tid % 10;
    float s = bout[o];
    const _Float16* hrow = h1 + (size_t)b * 512;
    const float* wrow = Wout + (size_t)o * 512;
    for (int k = 0; k < 512; ++k) s += (float)hrow[k] * wrow[k];
    out[tid] = s;
}

extern "C" void kernel_launch(void* const* d_in, const int* in_sizes, int n_in,
                              void* d_out, int out_size, void* d_ws, size_t ws_size,
                              hipStream_t stream) {
    const float* xb    = (const float*)d_in[0];
    const float* W_ih0 = (const float*)d_in[1];
    const float* W_hh0 = (const float*)d_in[2];
    const float* b0    = (const float*)d_in[3];
    const float* W_ih1 = (const float*)d_in[4];
    const float* W_hh1 = (const float*)d_in[5];
    const float* b1    = (const float*)d_in[6];
    const float* W_out = (const float*)d_in[7];
    const float* b_out = (const float*)d_in[8];
    float* out = (float*)d_out;

    char* ws = (char*)d_ws;
    size_t off = 0;
    auto alloc = [&](size_t bytes) -> void* {
        void* p = ws + off;
        off += (bytes + 255) & ~(size_t)255;
        return p;
    };
    // ~57 MB << 256 MiB ws
    _Float16* xb16 = (_Float16*)alloc((size_t)Bsz * Lsz * 2);
    _Float16* Wc0  = (_Float16*)alloc((size_t)2048 * 640 * 2);
    _Float16* Wc1  = (_Float16*)alloc((size_t)2048 * 1024 * 2);
    _Float16* h00  = (_Float16*)alloc((size_t)Bsz * 512 * 2);
    _Float16* h01  = (_Float16*)alloc((size_t)Bsz * 512 * 2);
    _Float16* h10  = (_Float16*)alloc((size_t)Bsz * 512 * 2);
    _Float16* h11  = (_Float16*)alloc((size_t)Bsz * 512 * 2);
    float* c0 = (float*)alloc((size_t)Bsz * 512 * 4);
    float* c1 = (float*)alloc((size_t)Bsz * 512 * 4);

    cvt_f32_f16<<<2048, 256, 0, stream>>>(xb, xb16, Bsz * Lsz / 4);
    pack_w<<<1280, 256, 0, stream>>>(W_ih0, W_hh0, Wc0, 128);
    pack_w<<<2048, 256, 0, stream>>>(W_ih1, W_hh1, Wc1, 512);

    hipMemsetAsync(h00, 0, (size_t)Bsz * 512 * 2, stream);
    hipMemsetAsync(h10, 0, (size_t)Bsz * 512 * 2, stream);
    hipMemsetAsync(c0, 0, (size_t)Bsz * 512 * 4, stream);
    hipMemsetAsync(c1, 0, (size_t)Bsz * 512 * 4, stream);

    for (int r = 0; r <= Tsz; ++r) {
        int t0 = (r < Tsz) ? r : -1;
        int t1 = r - 1;
        lstm_round<<<dim3(256), 512, 0, stream>>>(t0, t1,
            xb16, Wc0, b0, c0, h00, h01,
            Wc1, b1, c1, h10, h11);
    }

    // final h1 (t=63) written to h10
    proj_kernel<<<(Bsz * 10 + 255) / 256, 256, 0, stream>>>(h10, W_out, b_out, out);
}